// Round 4
// baseline (118.760 us; speedup 1.0000x reference)
//
#include <hip/hip_runtime.h>
#include <hip/hip_bf16.h>
#include <cstddef>
#include <cstdint>

#define DM 512
#define DK 64
#define BB 4
#define S4 4096
#define NR (BB*S4)      // 16384 rows
#define KVB 64
#define QBLOCK 128      // 4 waves x 32 q-rows
#define LP 72           // attn LDS row pitch in ushorts

typedef float   f32x16 __attribute__((ext_vector_type(16)));
typedef short   bf16x8 __attribute__((ext_vector_type(8)));

// Q pre-scale: 1/sqrt(64) * log2(e)  (softmax runs in exp2 domain)
#define QSCALE 0.18033688011112042f

__device__ __forceinline__ ushort bf16bits(float f) {
    __hip_bfloat16 h = __float2bfloat16(f);
    return *reinterpret_cast<ushort*>(&h);
}

// ---------------- W^T hi/lo prep: Wt[c][k], c in [0,192) ----------------
__global__ __launch_bounds__(256) void prep_w(
    const float* __restrict__ wq, const float* __restrict__ wk,
    const float* __restrict__ wv,
    ushort* __restrict__ Wth, ushort* __restrict__ Wtl)
{
    const int id = blockIdx.x * 256 + threadIdx.x;   // 98304 total
    const int c  = id >> 9, k = id & 511;
    const float* src = (c < 64) ? wq : (c < 128) ? wk : wv;
    const float wval = src[k * DK + (c & 63)];
    const ushort h  = bf16bits(wval);
    __hip_bfloat16 hh = *reinterpret_cast<const __hip_bfloat16*>(&h);
    const float hf  = __bfloat162float(hh);
    Wth[(size_t)c * DM + k] = h;
    Wtl[(size_t)c * DM + k] = bf16bits(wval - hf);
}

// ---------------- QKV projection via MFMA (hi/lo bf16 split) ----------------
// BM=128 rows/block, 4 waves x 32 rows, all 192 cols. x read once from HBM.
__global__ __launch_bounds__(256) void qkv_mfma(
    const float* __restrict__ x,
    const ushort* __restrict__ Wth, const ushort* __restrict__ Wtl,
    const float* __restrict__ bq, const float* __restrict__ bk,
    const float* __restrict__ bv,
    ushort* __restrict__ Qb, ushort* __restrict__ Kb, ushort* __restrict__ Vb)
{
    __shared__ ushort Xh[128 * 64];   // 16 KB, XOR-16 swizzled, pitch 128 B
    __shared__ ushort Xl[128 * 64];

    const int tid  = threadIdx.x;
    const int w    = tid >> 6;
    const int lane = tid & 63;
    const int hi   = lane >> 5;
    const int q5   = lane & 31;
    const size_t row0 = (size_t)blockIdx.x * 128;
    const int arow = w * 32 + q5;

    float4 xr[8];
    auto gx = [&](int ko) {
        #pragma unroll
        for (int i = 0; i < 8; ++i) {
            const int idx = i * 256 + tid, r = idx >> 4, kc = idx & 15;
            xr[i] = *(const float4*)&x[(row0 + r) * DM + ko * 64 + kc * 4];
        }
    };

    f32x16 acc[6];
    #pragma unroll
    for (int n = 0; n < 6; ++n) acc[n] = (f32x16){};

    gx(0);

    for (int ko = 0; ko < 8; ++ko) {
        __syncthreads();   // previous tile's LDS reads complete
        #pragma unroll
        for (int i = 0; i < 8; ++i) {
            const int idx = i * 256 + tid, r = idx >> 4, kc = idx & 15;
            const float f[4] = {xr[i].x, xr[i].y, xr[i].z, xr[i].w};
            ushort hs[4], ls[4];
            #pragma unroll
            for (int j = 0; j < 4; ++j) {
                hs[j] = bf16bits(f[j]);
                __hip_bfloat16 hh = *reinterpret_cast<const __hip_bfloat16*>(&hs[j]);
                ls[j] = bf16bits(f[j] - __bfloat162float(hh));
            }
            const int byte = (r * 128 + kc * 8) ^ ((r & 7) << 4);
            uint2 hv = {(uint32_t)hs[0] | ((uint32_t)hs[1] << 16),
                        (uint32_t)hs[2] | ((uint32_t)hs[3] << 16)};
            uint2 lv = {(uint32_t)ls[0] | ((uint32_t)ls[1] << 16),
                        (uint32_t)ls[2] | ((uint32_t)ls[3] << 16)};
            *reinterpret_cast<uint2*>((char*)Xh + byte) = hv;
            *reinterpret_cast<uint2*>((char*)Xl + byte) = lv;
        }
        __syncthreads();   // tile ready
        if (ko < 7) gx(ko + 1);   // prefetch next x tile (latency under MFMAs)

        #pragma unroll
        for (int ks = 0; ks < 4; ++ks) {
            const int abyte = (arow * 128 + ks * 32 + hi * 16) ^ ((arow & 7) << 4);
            const bf16x8 ah = *reinterpret_cast<const bf16x8*>((char*)Xh + abyte);
            const bf16x8 al = *reinterpret_cast<const bf16x8*>((char*)Xl + abyte);
            const int koff = ko * 64 + ks * 16 + hi * 8;
            #pragma unroll
            for (int n = 0; n < 6; ++n) {
                const size_t wb = (size_t)(n * 32 + q5) * DM + koff;
                const bf16x8 bh = *reinterpret_cast<const bf16x8*>(Wth + wb);
                const bf16x8 bl = *reinterpret_cast<const bf16x8*>(Wtl + wb);
                acc[n] = __builtin_amdgcn_mfma_f32_32x32x16_bf16(ah, bh, acc[n], 0, 0, 0);
                acc[n] = __builtin_amdgcn_mfma_f32_32x32x16_bf16(al, bh, acc[n], 0, 0, 0);
                acc[n] = __builtin_amdgcn_mfma_f32_32x32x16_bf16(ah, bl, acc[n], 0, 0, 0);
            }
        }
    }

    // epilogue: bias add (+ QSCALE for Q), bf16 store
    const float* bp[3] = {bq, bk, bv};
    ushort*      op[3] = {Qb, Kb, Vb};
    #pragma unroll
    for (int n = 0; n < 6; ++n) {
        const float bias = bp[n >> 1][(n & 1) * 32 + q5];
        #pragma unroll
        for (int r = 0; r < 16; ++r) {
            const int rr = (r & 3) + 8 * (r >> 2) + 4 * hi;
            const size_t grow = row0 + w * 32 + rr;
            float v = acc[n][r] + bias;
            if (n < 2) v *= QSCALE;
            op[n >> 1][grow * DK + (n & 1) * 32 + q5] = bf16bits(v);
        }
    }
}

// ---------------- V transpose: [b][s][dv] -> Vt[b][dv][s] ----------------
__global__ __launch_bounds__(256) void transpose_v(
    const ushort* __restrict__ V, ushort* __restrict__ Vt)
{
    __shared__ ushort t[64 * 72];
    const int tid = threadIdx.x;
    const int s0  = blockIdx.x * 64;
    const int b   = blockIdx.y;
    const int sr  = tid >> 2, c = tid & 3;

    const uint4* src = reinterpret_cast<const uint4*>(
        V + ((size_t)b * S4 + s0 + sr) * DK + c * 16);
    uint4 v0 = src[0], v1 = src[1];
    *reinterpret_cast<uint4*>(&t[sr * 72 + c * 16])     = v0;
    *reinterpret_cast<uint4*>(&t[sr * 72 + c * 16 + 8]) = v1;
    __syncthreads();

    const int dv = tid >> 2;
    alignas(16) ushort o[16];
    #pragma unroll
    for (int i = 0; i < 16; ++i) o[i] = t[(c * 16 + i) * 72 + dv];
    uint4* dst = reinterpret_cast<uint4*>(
        Vt + ((size_t)b * DK + dv) * S4 + s0 + c * 16);
    dst[0] = *reinterpret_cast<const uint4*>(&o[0]);
    dst[1] = *reinterpret_cast<const uint4*>(&o[8]);
}

// ---------------- MFMA flash attention (unchanged from round 3) ----------------
__global__ __launch_bounds__(256, 2) void attn_mfma(
    const ushort* __restrict__ Qb, const ushort* __restrict__ Kb,
    const ushort* __restrict__ Vt,
    float* __restrict__ Opart, float* __restrict__ Mpart,
    float* __restrict__ Lpart, float* __restrict__ out, int sigma)
{
    __shared__ ushort Ks[64 * LP];
    __shared__ ushort Vs[64 * LP];

    const int tid  = threadIdx.x;
    const int w    = tid >> 6;
    const int lane = tid & 63;
    const int hi   = lane >> 5;
    const int q5   = lane & 31;
    const int b    = blockIdx.y, ci = blockIdx.z;
    const int klen = S4 / sigma, kv0 = ci * klen;
    const int qrow = blockIdx.x * QBLOCK + w * 32 + q5;

    const int c0 = tid, c1 = tid + 256;
    const int r0 = c0 >> 3, cc0 = c0 & 7;
    const int r1 = c1 >> 3, cc1 = c1 & 7;

    bf16x8 qf[4];
    {
        const ushort* qp = Qb + ((size_t)b * S4 + qrow) * DK;
        #pragma unroll
        for (int s = 0; s < 4; ++s)
            qf[s] = *reinterpret_cast<const bf16x8*>(qp + s * 16 + hi * 8);
    }

    f32x16 oacc0 = {}, oacc1 = {};
    float m = -1e30f, lsum = 0.0f;

    uint4 kreg0, kreg1, vreg0, vreg1;
    auto gload = [&](int t) {
        const ushort* gK = Kb + ((size_t)b * S4 + kv0 + t * KVB) * DK;
        const ushort* gV = Vt + (size_t)b * DK * S4 + (kv0 + t * KVB);
        kreg0 = *reinterpret_cast<const uint4*>(gK + r0 * DK + cc0 * 8);
        kreg1 = *reinterpret_cast<const uint4*>(gK + r1 * DK + cc1 * 8);
        vreg0 = *reinterpret_cast<const uint4*>(gV + (size_t)r0 * S4 + cc0 * 8);
        vreg1 = *reinterpret_cast<const uint4*>(gV + (size_t)r1 * S4 + cc1 * 8);
    };

    const int nt = klen / KVB;
    gload(0);

    for (int t = 0; t < nt; ++t) {
        __syncthreads();
        *reinterpret_cast<uint4*>(&Ks[r0 * LP + cc0 * 8]) = kreg0;
        *reinterpret_cast<uint4*>(&Ks[r1 * LP + cc1 * 8]) = kreg1;
        *reinterpret_cast<uint4*>(&Vs[r0 * LP + cc0 * 8]) = vreg0;
        *reinterpret_cast<uint4*>(&Vs[r1 * LP + cc1 * 8]) = vreg1;
        __syncthreads();
        if (t + 1 < nt) gload(t + 1);

        #pragma unroll
        for (int sub = 0; sub < 2; ++sub) {
            const int kvr = sub * 32 + q5;
            bf16x8 kf[4];
            #pragma unroll
            for (int s = 0; s < 4; ++s)
                kf[s] = *reinterpret_cast<const bf16x8*>(
                    &Ks[kvr * LP + (2 * s + hi) * 8]);
            f32x16 sacc = {};
            #pragma unroll
            for (int s = 0; s < 4; ++s)
                sacc = __builtin_amdgcn_mfma_f32_32x32x16_bf16(
                    kf[s], qf[s], sacc, 0, 0, 0);

            float pmax = sacc[0];
            #pragma unroll
            for (int r = 1; r < 16; ++r) pmax = fmaxf(pmax, sacc[r]);
            pmax = fmaxf(pmax, __shfl_xor(pmax, 32));

            if (__any(pmax > m + 8.0f)) {
                const float mn   = fmaxf(m, pmax);
                const float corr = exp2f(m - mn);
                lsum *= corr;
                #pragma unroll
                for (int r = 0; r < 16; ++r) {
                    const int qq = (r & 3) + 8 * (r >> 2) + 4 * hi;
                    const float cq = __shfl(corr, qq);
                    oacc0[r] *= cq; oacc1[r] *= cq;
                }
                m = mn;
            }

            float p[16];
            float ts = 0.0f;
            #pragma unroll
            for (int r = 0; r < 16; ++r) {
                p[r] = exp2f(sacc[r] - m);
                ts += p[r];
            }
            lsum += ts + __shfl_xor(ts, 32);

            uint32_t wd[8];
            #pragma unroll
            for (int g = 0; g < 4; ++g) {
                #pragma unroll
                for (int k = 0; k < 2; ++k) {
                    wd[2 * g + k] =
                        (uint32_t)bf16bits(p[4 * g + 2 * k])
                      | ((uint32_t)bf16bits(p[4 * g + 2 * k + 1]) << 16);
                }
            }
            const uint32_t e0 = __shfl_xor(hi ? wd[0] : wd[2], 32);
            const uint32_t e1 = __shfl_xor(hi ? wd[1] : wd[3], 32);
            const uint32_t e2 = __shfl_xor(hi ? wd[4] : wd[6], 32);
            const uint32_t e3 = __shfl_xor(hi ? wd[5] : wd[7], 32);
            union { uint32_t u[4]; bf16x8 v; } pa0, pa1;
            pa0.u[0] = hi ? e0 : wd[0];
            pa0.u[1] = hi ? e1 : wd[1];
            pa0.u[2] = hi ? wd[2] : e0;
            pa0.u[3] = hi ? wd[3] : e1;
            pa1.u[0] = hi ? e2 : wd[4];
            pa1.u[1] = hi ? e3 : wd[5];
            pa1.u[2] = hi ? wd[6] : e2;
            pa1.u[3] = hi ? wd[7] : e3;

            #pragma unroll
            for (int h = 0; h < 2; ++h) {
                const int dv = h * 32 + q5;
                #pragma unroll
                for (int tt = 0; tt < 2; ++tt) {
                    const bf16x8 vf = *reinterpret_cast<const bf16x8*>(
                        &Vs[dv * LP + (sub * 4 + tt * 2 + hi) * 8]);
                    if (h == 0)
                        oacc0 = __builtin_amdgcn_mfma_f32_32x32x16_bf16(
                            tt == 0 ? pa0.v : pa1.v, vf, oacc0, 0, 0, 0);
                    else
                        oacc1 = __builtin_amdgcn_mfma_f32_32x32x16_bf16(
                            tt == 0 ? pa0.v : pa1.v, vf, oacc1, 0, 0, 0);
                }
            }
        }
    }

    if (sigma == 1) {
        #pragma unroll
        for (int r = 0; r < 16; ++r) {
            const int qq = (r & 3) + 8 * (r >> 2) + 4 * hi;
            const float lq  = __shfl(lsum, qq);
            const float inv = 1.0f / lq;
            const size_t row = (size_t)b * S4 + blockIdx.x * QBLOCK + w * 32 + qq;
            out[row * DK + q5]      = oacc0[r] * inv;
            out[row * DK + 32 + q5] = oacc1[r] * inv;
        }
    } else {
        if (hi == 0) {
            const size_t row = (size_t)b * S4 + qrow;
            Mpart[(size_t)ci * NR + row] = m;
            Lpart[(size_t)ci * NR + row] = lsum;
        }
        #pragma unroll
        for (int r = 0; r < 16; ++r) {
            const int qq = (r & 3) + 8 * (r >> 2) + 4 * hi;
            const size_t row = (size_t)b * S4 + blockIdx.x * QBLOCK + w * 32 + qq;
            float* op = Opart + ((size_t)ci * NR + row) * DK;
            op[q5]      = oacc0[r];
            op[32 + q5] = oacc1[r];
        }
    }
}

// ---------------- merge KV-split partials (exp2 domain) ----------------
__global__ __launch_bounds__(256) void attn_reduce(
    const float* __restrict__ Opart, const float* __restrict__ Mpart,
    const float* __restrict__ Lpart, float* __restrict__ out, int sigma)
{
    const int e   = blockIdx.x * 256 + threadIdx.x;
    const int row = e >> 6;
    const int d   = e & 63;

    float M = -1e30f;
    for (int i = 0; i < sigma; ++i) M = fmaxf(M, Mpart[(size_t)i * NR + row]);
    float L = 0.0f, O = 0.0f;
    for (int i = 0; i < sigma; ++i) {
        const float wgt = exp2f(Mpart[(size_t)i * NR + row] - M);
        L = fmaf(wgt, Lpart[(size_t)i * NR + row], L);
        O = fmaf(wgt, Opart[((size_t)i * NR + row) * DK + d], O);
    }
    out[e] = O / L;
}

extern "C" void kernel_launch(void* const* d_in, const int* in_sizes, int n_in,
                              void* d_out, int out_size, void* d_ws, size_t ws_size,
                              hipStream_t stream)
{
    const float* x  = (const float*)d_in[0];
    const float* wq = (const float*)d_in[1];
    const float* bq = (const float*)d_in[2];
    const float* wk = (const float*)d_in[3];
    const float* bk = (const float*)d_in[4];
    const float* wv = (const float*)d_in[5];
    const float* bv = (const float*)d_in[6];

    char* ws = (char*)d_ws;
    const size_t MB2  = (size_t)NR * DK * 2;     // 2 MB per bf16 matrix
    const size_t WTSZ = (size_t)192 * DM * 2;    // 192 KB per Wt matrix

    ushort* Qb  = (ushort*)(ws);
    ushort* Kb  = (ushort*)(ws + MB2);
    ushort* Vb  = (ushort*)(ws + 2 * MB2);
    ushort* Vt  = (ushort*)(ws + 3 * MB2);
    ushort* Wth = (ushort*)(ws + 4 * MB2);
    ushort* Wtl = (ushort*)(ws + 4 * MB2 + WTSZ);

    const size_t POFF = 4 * MB2 + 2 * WTSZ;

    int sigma = 1;
    const int cand[2] = {4, 2};
    for (int i = 0; i < 2; ++i) {
        const int s = cand[i];
        const size_t need = POFF + (size_t)s * ((size_t)NR * DK * 4 + (size_t)NR * 8);
        if (need <= ws_size) { sigma = s; break; }
    }

    float* Opart = (float*)(ws + POFF);
    float* Mpart = (float*)(ws + POFF + (size_t)sigma * NR * DK * 4);
    float* Lpart = Mpart + (size_t)sigma * NR;

    prep_w<<<384, 256, 0, stream>>>(wq, wk, wv, Wth, Wtl);
    qkv_mfma<<<NR / 128, 256, 0, stream>>>(x, Wth, Wtl, bq, bk, bv, Qb, Kb, Vb);
    transpose_v<<<dim3(S4 / 64, BB), 256, 0, stream>>>(Vb, Vt);

    dim3 grid(S4 / QBLOCK, BB, sigma);
    attn_mfma<<<grid, 256, 0, stream>>>(Qb, Kb, Vt, Opart, Mpart, Lpart,
                                        (float*)d_out, sigma);

    if (sigma > 1)
        attn_reduce<<<(NR * DK) / 256, 256, 0, stream>>>(Opart, Mpart, Lpart,
                                                         (float*)d_out, sigma);
}

// Round 5
// 92.549 us; speedup vs baseline: 1.2832x; 1.2832x over previous
//
#include <hip/hip_runtime.h>
#include <hip/hip_bf16.h>
#include <cstddef>
#include <cstdint>

#define DM 512
#define DK 64
#define BB 4
#define S4 4096
#define NR (BB*S4)      // 16384 rows
#define KVB 64
#define QBLOCK 128      // 4 waves x 32 q-rows
#define LP 72           // attn LDS row pitch in ushorts

typedef float   f32x16 __attribute__((ext_vector_type(16)));
typedef short   bf16x8 __attribute__((ext_vector_type(8)));

// Q pre-scale: 1/sqrt(64) * log2(e)  (softmax runs in exp2 domain)
#define QSCALE 0.18033688011112042f

__device__ __forceinline__ ushort bf16bits(float f) {
    __hip_bfloat16 h = __float2bfloat16(f);
    return *reinterpret_cast<ushort*>(&h);
}

// ---------------- W prep: fragment-major hi/lo bf16 ----------------
// Wf[seg][col][e], seg=(ko*4+ks)*2+khalf, col in [0,192), e in [0,8)
// -> a wave's B-fragment load (32 lanes x 16B) is one contiguous 512B run.
__global__ __launch_bounds__(256) void prep_w(
    const float* __restrict__ wq, const float* __restrict__ wk,
    const float* __restrict__ wv,
    ushort* __restrict__ Wfh, ushort* __restrict__ Wfl)
{
    const int id = blockIdx.x * 256 + threadIdx.x;   // 98304 total
    const int c  = id >> 9, k = id & 511;
    const float* src = (c < 64) ? wq : (c < 128) ? wk : wv;
    const float wval = src[k * DK + (c & 63)];
    const ushort h  = bf16bits(wval);
    __hip_bfloat16 hh = *reinterpret_cast<const __hip_bfloat16*>(&h);
    const ushort l  = bf16bits(wval - __bfloat162float(hh));
    const int ko = k >> 6, ks = (k >> 4) & 3, kh = (k >> 3) & 1, e = k & 7;
    const size_t idx = ((size_t)((ko * 4 + ks) * 2 + kh) * 192 + c) * 8 + e;
    Wfh[idx] = h;
    Wfl[idx] = l;
}

// ---------------- QKV projection via MFMA (hi/lo bf16 split) ----------------
// BM=64 rows/block (grid=256 -> 1 block/CU on all CUs), 4 waves as
// 2 row-groups x 2 col-groups; wave tile 32 rows x 96 cols (n=3 accs).
// x read once from HBM; W read fragment-major (coalesced, L2-resident).
__global__ __launch_bounds__(256) void qkv_mfma(
    const float* __restrict__ x,
    const ushort* __restrict__ Wfh, const ushort* __restrict__ Wfl,
    const float* __restrict__ bq, const float* __restrict__ bk,
    const float* __restrict__ bv,
    ushort* __restrict__ Qb, ushort* __restrict__ Kb, ushort* __restrict__ Vb)
{
    __shared__ ushort Xh[64 * 64];   // 8 KB, XOR-16 swizzled, pitch 128 B
    __shared__ ushort Xl[64 * 64];

    const int tid  = threadIdx.x;
    const int w    = tid >> 6;
    const int lane = tid & 63;
    const int hi   = lane >> 5;       // k-half selector
    const int q5   = lane & 31;
    const int wr   = w >> 1, wc = w & 1;
    const size_t row0 = (size_t)blockIdx.x * 64;
    const int arow = wr * 32 + q5;

    float4 xr[4];
    auto gx = [&](int ko) {
        #pragma unroll
        for (int i = 0; i < 4; ++i) {
            const int idx = i * 256 + tid, r = idx >> 4, kc = idx & 15;
            xr[i] = *(const float4*)&x[(row0 + r) * DM + ko * 64 + kc * 4];
        }
    };

    f32x16 acc[3];
    #pragma unroll
    for (int n = 0; n < 3; ++n) acc[n] = (f32x16){};

    gx(0);

    for (int ko = 0; ko < 8; ++ko) {
        __syncthreads();   // previous tile's LDS reads complete
        #pragma unroll
        for (int i = 0; i < 4; ++i) {
            const int idx = i * 256 + tid, r = idx >> 4, kc = idx & 15;
            const float f[4] = {xr[i].x, xr[i].y, xr[i].z, xr[i].w};
            ushort hs[4], ls[4];
            #pragma unroll
            for (int j = 0; j < 4; ++j) {
                hs[j] = bf16bits(f[j]);
                __hip_bfloat16 hh = *reinterpret_cast<const __hip_bfloat16*>(&hs[j]);
                ls[j] = bf16bits(f[j] - __bfloat162float(hh));
            }
            const int byte = (r * 128 + kc * 8) ^ ((r & 7) << 4);
            uint2 hv = {(uint32_t)hs[0] | ((uint32_t)hs[1] << 16),
                        (uint32_t)hs[2] | ((uint32_t)hs[3] << 16)};
            uint2 lv = {(uint32_t)ls[0] | ((uint32_t)ls[1] << 16),
                        (uint32_t)ls[2] | ((uint32_t)ls[3] << 16)};
            *reinterpret_cast<uint2*>((char*)Xh + byte) = hv;
            *reinterpret_cast<uint2*>((char*)Xl + byte) = lv;
        }
        __syncthreads();   // tile ready
        if (ko < 7) gx(ko + 1);   // prefetch next x tile under the MFMAs

        #pragma unroll
        for (int ks = 0; ks < 4; ++ks) {
            const int abyte = (arow * 128 + ks * 32 + hi * 16) ^ ((arow & 7) << 4);
            const bf16x8 ah = *reinterpret_cast<const bf16x8*>((char*)Xh + abyte);
            const bf16x8 al = *reinterpret_cast<const bf16x8*>((char*)Xl + abyte);
            const int seg = (ko * 4 + ks) * 2 + hi;
            #pragma unroll
            for (int n = 0; n < 3; ++n) {
                const size_t wb = ((size_t)seg * 192 + wc * 96 + n * 32 + q5) * 8;
                const bf16x8 bh = *reinterpret_cast<const bf16x8*>(Wfh + wb);
                const bf16x8 bl = *reinterpret_cast<const bf16x8*>(Wfl + wb);
                acc[n] = __builtin_amdgcn_mfma_f32_32x32x16_bf16(ah, bh, acc[n], 0, 0, 0);
                acc[n] = __builtin_amdgcn_mfma_f32_32x32x16_bf16(al, bh, acc[n], 0, 0, 0);
                acc[n] = __builtin_amdgcn_mfma_f32_32x32x16_bf16(ah, bl, acc[n], 0, 0, 0);
            }
        }
    }

    // epilogue: bias add (+ QSCALE for Q), bf16 store
    const float* bp[3] = {bq, bk, bv};
    ushort*      op[3] = {Qb, Kb, Vb};
    #pragma unroll
    for (int n = 0; n < 3; ++n) {
        const int cidx = wc * 3 + n;          // 0..5
        const int mi = cidx >> 1, half = cidx & 1;
        const float bias = bp[mi][half * 32 + q5];
        #pragma unroll
        for (int r = 0; r < 16; ++r) {
            const int rr = (r & 3) + 8 * (r >> 2) + 4 * hi;
            const size_t grow = row0 + wr * 32 + rr;
            float v = acc[n][r] + bias;
            if (mi == 0) v *= QSCALE;
            op[mi][grow * DK + half * 32 + q5] = bf16bits(v);
        }
    }
}

// ---------------- V transpose: [b][s][dv] -> Vt[b][dv][s] ----------------
__global__ __launch_bounds__(256) void transpose_v(
    const ushort* __restrict__ V, ushort* __restrict__ Vt)
{
    __shared__ ushort t[64 * 72];
    const int tid = threadIdx.x;
    const int s0  = blockIdx.x * 64;
    const int b   = blockIdx.y;
    const int sr  = tid >> 2, c = tid & 3;

    const uint4* src = reinterpret_cast<const uint4*>(
        V + ((size_t)b * S4 + s0 + sr) * DK + c * 16);
    uint4 v0 = src[0], v1 = src[1];
    *reinterpret_cast<uint4*>(&t[sr * 72 + c * 16])     = v0;
    *reinterpret_cast<uint4*>(&t[sr * 72 + c * 16 + 8]) = v1;
    __syncthreads();

    const int dv = tid >> 2;
    alignas(16) ushort o[16];
    #pragma unroll
    for (int i = 0; i < 16; ++i) o[i] = t[(c * 16 + i) * 72 + dv];
    uint4* dst = reinterpret_cast<uint4*>(
        Vt + ((size_t)b * DK + dv) * S4 + s0 + c * 16);
    dst[0] = *reinterpret_cast<const uint4*>(&o[0]);
    dst[1] = *reinterpret_cast<const uint4*>(&o[8]);
}

// ---------------- MFMA flash attention (unchanged, validated) ----------------
__global__ __launch_bounds__(256, 2) void attn_mfma(
    const ushort* __restrict__ Qb, const ushort* __restrict__ Kb,
    const ushort* __restrict__ Vt,
    float* __restrict__ Opart, float* __restrict__ Mpart,
    float* __restrict__ Lpart, float* __restrict__ out, int sigma)
{
    __shared__ ushort Ks[64 * LP];
    __shared__ ushort Vs[64 * LP];

    const int tid  = threadIdx.x;
    const int w    = tid >> 6;
    const int lane = tid & 63;
    const int hi   = lane >> 5;
    const int q5   = lane & 31;
    const int b    = blockIdx.y, ci = blockIdx.z;
    const int klen = S4 / sigma, kv0 = ci * klen;
    const int qrow = blockIdx.x * QBLOCK + w * 32 + q5;

    const int c0 = tid, c1 = tid + 256;
    const int r0 = c0 >> 3, cc0 = c0 & 7;
    const int r1 = c1 >> 3, cc1 = c1 & 7;

    bf16x8 qf[4];
    {
        const ushort* qp = Qb + ((size_t)b * S4 + qrow) * DK;
        #pragma unroll
        for (int s = 0; s < 4; ++s)
            qf[s] = *reinterpret_cast<const bf16x8*>(qp + s * 16 + hi * 8);
    }

    f32x16 oacc0 = {}, oacc1 = {};
    float m = -1e30f, lsum = 0.0f;

    uint4 kreg0, kreg1, vreg0, vreg1;
    auto gload = [&](int t) {
        const ushort* gK = Kb + ((size_t)b * S4 + kv0 + t * KVB) * DK;
        const ushort* gV = Vt + (size_t)b * DK * S4 + (kv0 + t * KVB);
        kreg0 = *reinterpret_cast<const uint4*>(gK + r0 * DK + cc0 * 8);
        kreg1 = *reinterpret_cast<const uint4*>(gK + r1 * DK + cc1 * 8);
        vreg0 = *reinterpret_cast<const uint4*>(gV + (size_t)r0 * S4 + cc0 * 8);
        vreg1 = *reinterpret_cast<const uint4*>(gV + (size_t)r1 * S4 + cc1 * 8);
    };

    const int nt = klen / KVB;
    gload(0);

    for (int t = 0; t < nt; ++t) {
        __syncthreads();
        *reinterpret_cast<uint4*>(&Ks[r0 * LP + cc0 * 8]) = kreg0;
        *reinterpret_cast<uint4*>(&Ks[r1 * LP + cc1 * 8]) = kreg1;
        *reinterpret_cast<uint4*>(&Vs[r0 * LP + cc0 * 8]) = vreg0;
        *reinterpret_cast<uint4*>(&Vs[r1 * LP + cc1 * 8]) = vreg1;
        __syncthreads();
        if (t + 1 < nt) gload(t + 1);

        #pragma unroll
        for (int sub = 0; sub < 2; ++sub) {
            const int kvr = sub * 32 + q5;
            bf16x8 kf[4];
            #pragma unroll
            for (int s = 0; s < 4; ++s)
                kf[s] = *reinterpret_cast<const bf16x8*>(
                    &Ks[kvr * LP + (2 * s + hi) * 8]);
            f32x16 sacc = {};
            #pragma unroll
            for (int s = 0; s < 4; ++s)
                sacc = __builtin_amdgcn_mfma_f32_32x32x16_bf16(
                    kf[s], qf[s], sacc, 0, 0, 0);

            float pmax = sacc[0];
            #pragma unroll
            for (int r = 1; r < 16; ++r) pmax = fmaxf(pmax, sacc[r]);
            pmax = fmaxf(pmax, __shfl_xor(pmax, 32));

            if (__any(pmax > m + 8.0f)) {
                const float mn   = fmaxf(m, pmax);
                const float corr = exp2f(m - mn);
                lsum *= corr;
                #pragma unroll
                for (int r = 0; r < 16; ++r) {
                    const int qq = (r & 3) + 8 * (r >> 2) + 4 * hi;
                    const float cq = __shfl(corr, qq);
                    oacc0[r] *= cq; oacc1[r] *= cq;
                }
                m = mn;
            }

            float p[16];
            float ts = 0.0f;
            #pragma unroll
            for (int r = 0; r < 16; ++r) {
                p[r] = exp2f(sacc[r] - m);
                ts += p[r];
            }
            lsum += ts + __shfl_xor(ts, 32);

            uint32_t wd[8];
            #pragma unroll
            for (int g = 0; g < 4; ++g) {
                #pragma unroll
                for (int k = 0; k < 2; ++k) {
                    wd[2 * g + k] =
                        (uint32_t)bf16bits(p[4 * g + 2 * k])
                      | ((uint32_t)bf16bits(p[4 * g + 2 * k + 1]) << 16);
                }
            }
            const uint32_t e0 = __shfl_xor(hi ? wd[0] : wd[2], 32);
            const uint32_t e1 = __shfl_xor(hi ? wd[1] : wd[3], 32);
            const uint32_t e2 = __shfl_xor(hi ? wd[4] : wd[6], 32);
            const uint32_t e3 = __shfl_xor(hi ? wd[5] : wd[7], 32);
            union { uint32_t u[4]; bf16x8 v; } pa0, pa1;
            pa0.u[0] = hi ? e0 : wd[0];
            pa0.u[1] = hi ? e1 : wd[1];
            pa0.u[2] = hi ? wd[2] : e0;
            pa0.u[3] = hi ? wd[3] : e1;
            pa1.u[0] = hi ? e2 : wd[4];
            pa1.u[1] = hi ? e3 : wd[5];
            pa1.u[2] = hi ? wd[6] : e2;
            pa1.u[3] = hi ? wd[7] : e3;

            #pragma unroll
            for (int h = 0; h < 2; ++h) {
                const int dv = h * 32 + q5;
                #pragma unroll
                for (int tt = 0; tt < 2; ++tt) {
                    const bf16x8 vf = *reinterpret_cast<const bf16x8*>(
                        &Vs[dv * LP + (sub * 4 + tt * 2 + hi) * 8]);
                    if (h == 0)
                        oacc0 = __builtin_amdgcn_mfma_f32_32x32x16_bf16(
                            tt == 0 ? pa0.v : pa1.v, vf, oacc0, 0, 0, 0);
                    else
                        oacc1 = __builtin_amdgcn_mfma_f32_32x32x16_bf16(
                            tt == 0 ? pa0.v : pa1.v, vf, oacc1, 0, 0, 0);
                }
            }
        }
    }

    if (sigma == 1) {
        #pragma unroll
        for (int r = 0; r < 16; ++r) {
            const int qq = (r & 3) + 8 * (r >> 2) + 4 * hi;
            const float lq  = __shfl(lsum, qq);
            const float inv = 1.0f / lq;
            const size_t row = (size_t)b * S4 + blockIdx.x * QBLOCK + w * 32 + qq;
            out[row * DK + q5]      = oacc0[r] * inv;
            out[row * DK + 32 + q5] = oacc1[r] * inv;
        }
    } else {
        if (hi == 0) {
            const size_t row = (size_t)b * S4 + qrow;
            Mpart[(size_t)ci * NR + row] = m;
            Lpart[(size_t)ci * NR + row] = lsum;
        }
        #pragma unroll
        for (int r = 0; r < 16; ++r) {
            const int qq = (r & 3) + 8 * (r >> 2) + 4 * hi;
            const size_t row = (size_t)b * S4 + blockIdx.x * QBLOCK + w * 32 + qq;
            float* op = Opart + ((size_t)ci * NR + row) * DK;
            op[q5]      = oacc0[r];
            op[32 + q5] = oacc1[r];
        }
    }
}

// ---------------- merge KV-split partials (exp2 domain) ----------------
__global__ __launch_bounds__(256) void attn_reduce(
    const float* __restrict__ Opart, const float* __restrict__ Mpart,
    const float* __restrict__ Lpart, float* __restrict__ out, int sigma)
{
    const int e   = blockIdx.x * 256 + threadIdx.x;
    const int row = e >> 6;
    const int d   = e & 63;

    float M = -1e30f;
    for (int i = 0; i < sigma; ++i) M = fmaxf(M, Mpart[(size_t)i * NR + row]);
    float L = 0.0f, O = 0.0f;
    for (int i = 0; i < sigma; ++i) {
        const float wgt = exp2f(Mpart[(size_t)i * NR + row] - M);
        L = fmaf(wgt, Lpart[(size_t)i * NR + row], L);
        O = fmaf(wgt, Opart[((size_t)i * NR + row) * DK + d], O);
    }
    out[e] = O / L;
}

extern "C" void kernel_launch(void* const* d_in, const int* in_sizes, int n_in,
                              void* d_out, int out_size, void* d_ws, size_t ws_size,
                              hipStream_t stream)
{
    const float* x  = (const float*)d_in[0];
    const float* wq = (const float*)d_in[1];
    const float* bq = (const float*)d_in[2];
    const float* wk = (const float*)d_in[3];
    const float* bk = (const float*)d_in[4];
    const float* wv = (const float*)d_in[5];
    const float* bv = (const float*)d_in[6];

    char* ws = (char*)d_ws;
    const size_t MB2  = (size_t)NR * DK * 2;     // 2 MB per bf16 matrix
    const size_t WTSZ = (size_t)192 * DM * 2;    // 192 KB per Wf matrix

    ushort* Qb  = (ushort*)(ws);
    ushort* Kb  = (ushort*)(ws + MB2);
    ushort* Vb  = (ushort*)(ws + 2 * MB2);
    ushort* Vt  = (ushort*)(ws + 3 * MB2);
    ushort* Wfh = (ushort*)(ws + 4 * MB2);
    ushort* Wfl = (ushort*)(ws + 4 * MB2 + WTSZ);

    const size_t POFF = 4 * MB2 + 2 * WTSZ;

    int sigma = 1;
    const int cand[2] = {4, 2};
    for (int i = 0; i < 2; ++i) {
        const int s = cand[i];
        const size_t need = POFF + (size_t)s * ((size_t)NR * DK * 4 + (size_t)NR * 8);
        if (need <= ws_size) { sigma = s; break; }
    }

    float* Opart = (float*)(ws + POFF);
    float* Mpart = (float*)(ws + POFF + (size_t)sigma * NR * DK * 4);
    float* Lpart = Mpart + (size_t)sigma * NR;

    prep_w<<<384, 256, 0, stream>>>(wq, wk, wv, Wfh, Wfl);
    qkv_mfma<<<NR / 64, 256, 0, stream>>>(x, Wfh, Wfl, bq, bk, bv, Qb, Kb, Vb);
    transpose_v<<<dim3(S4 / 64, BB), 256, 0, stream>>>(Vb, Vt);

    dim3 grid(S4 / QBLOCK, BB, sigma);
    attn_mfma<<<grid, 256, 0, stream>>>(Qb, Kb, Vt, Opart, Mpart, Lpart,
                                        (float*)d_out, sigma);

    if (sigma > 1)
        attn_reduce<<<(NR * DK) / 256, 256, 0, stream>>>(Opart, Mpart, Lpart,
                                                         (float*)d_out, sigma);
}